// Round 1
// baseline (864.707 us; speedup 1.0000x reference)
//
#include <hip/hip_runtime.h>

// DDK_77644418777653: w[:,0]=1; w[:,k] = w[:,k-1] + alpha/w[:,k-1] - beta*x[:,k-1]
// M=262144 rows (independent), N=512 cols (sequential recurrence).
// Memory-bound: 1.05 GB traffic -> ~165 us floor at 6.3 TB/s.
//
// Strategy: 1 thread per row, 256 rows per block. Columns in chunks of 32,
// staged through LDS so both global loads and stores are fully coalesced
// (row-per-thread direct access would be 2KB-strided across lanes).
// LDS row stride 36 floats: 16B-aligned for b128 ops and conflict-free
// (start bank 4*((9t+q) mod 8) covers all 32 banks per 8-lane phase).

constexpr int MROWS  = 262144;
constexpr int NCOLS  = 512;
constexpr int BLOCK  = 256;   // threads = rows per block
constexpr int CC     = 32;    // columns per chunk
constexpr int LSTR   = 36;    // LDS row stride in floats (32 + 4 pad)

__global__ __launch_bounds__(BLOCK, 4) void ddk_recurrence(
    const float* __restrict__ in, const float* __restrict__ alpha,
    const float* __restrict__ beta, float* __restrict__ out) {
  __shared__ float tile[BLOCK * LSTR];  // 36 KB -> 4 blocks/CU
  const int tid  = threadIdx.x;
  const int row0 = blockIdx.x * BLOCK;
  const float a = alpha[0];
  const float b = beta[0];
  float w = 1.0f;  // w at column 0

  const float4* in4  = reinterpret_cast<const float4*>(in);
  float4*       out4 = reinterpret_cast<float4*>(out);
  constexpr int N4 = NCOLS / 4;  // 128 float4 per row

  for (int j = 0; j < NCOLS / CC; ++j) {
    const int c4 = j * (CC / 4);  // float4 column offset of this chunk

    // ---- cooperative load: rows [row0, row0+256) x cols [32j, 32j+32) ----
    // lanes 0..7 -> one row's 128B (8 contiguous 128B segments per wave)
#pragma unroll
    for (int it = 0; it < 8; ++it) {
      const int idx = it * BLOCK + tid;
      const int r = idx >> 3;
      const int q = idx & 7;
      const float4 v = in4[(row0 + r) * N4 + c4 + q];
      *reinterpret_cast<float4*>(&tile[r * LSTR + q * 4]) = v;
    }
    __syncthreads();

    // ---- compute: thread t owns row t of the tile ----
    float x[CC];
#pragma unroll
    for (int q = 0; q < 8; ++q) {
      const float4 v =
          *reinterpret_cast<const float4*>(&tile[tid * LSTR + q * 4]);
      x[q * 4 + 0] = v.x; x[q * 4 + 1] = v.y;
      x[q * 4 + 2] = v.z; x[q * 4 + 3] = v.w;
    }
#pragma unroll
    for (int c = 0; c < CC; ++c) {
      const float cur = w;            // out value at column 32j + c
      w = cur + a / cur - b * x[c];   // advance using input column 32j + c
      x[c] = cur;                     // reuse x[] as output staging
    }
#pragma unroll
    for (int q = 0; q < 8; ++q) {
      const float4 v = make_float4(x[q * 4 + 0], x[q * 4 + 1],
                                   x[q * 4 + 2], x[q * 4 + 3]);
      *reinterpret_cast<float4*>(&tile[tid * LSTR + q * 4]) = v;
    }
    __syncthreads();

    // ---- cooperative store: same coalesced mapping as load ----
#pragma unroll
    for (int it = 0; it < 8; ++it) {
      const int idx = it * BLOCK + tid;
      const int r = idx >> 3;
      const int q = idx & 7;
      const float4 v =
          *reinterpret_cast<const float4*>(&tile[r * LSTR + q * 4]);
      out4[(row0 + r) * N4 + c4 + q] = v;
    }
    __syncthreads();  // protect tile before next chunk's load
  }
}

extern "C" void kernel_launch(void* const* d_in, const int* in_sizes, int n_in,
                              void* d_out, int out_size, void* d_ws, size_t ws_size,
                              hipStream_t stream) {
  const float* in    = (const float*)d_in[0];
  const float* alpha = (const float*)d_in[1];
  const float* beta  = (const float*)d_in[2];
  float* out = (float*)d_out;
  dim3 grid(MROWS / BLOCK), block(BLOCK);
  hipLaunchKernelGGL(ddk_recurrence, grid, block, 0, stream,
                     in, alpha, beta, out);
}